// Round 6
// baseline (344.805 us; speedup 1.0000x reference)
//
#include <hip/hip_runtime.h>

typedef __attribute__((ext_vector_type(8))) short short8;
typedef __attribute__((ext_vector_type(4))) float f32x4;
typedef unsigned short ushort_t;

#define BAR()   __builtin_amdgcn_s_barrier()
#define LGKM0() asm volatile("s_waitcnt lgkmcnt(0)" ::: "memory")
#define LGKM8() asm volatile("s_waitcnt lgkmcnt(8)" ::: "memory")
#define VM6()   asm volatile("s_waitcnt vmcnt(6)" ::: "memory")
#define VM0()   asm volatile("s_waitcnt vmcnt(0)" ::: "memory")
#define PRIO(n) __builtin_amdgcn_s_setprio(n)
#define MFMA(a_, b_, c_) __builtin_amdgcn_mfma_f32_16x16x32_bf16(a_, b_, c_, 0, 0, 0)

// ---------- helpers ----------
__device__ __forceinline__ unsigned short f2bf(float f) {
  unsigned u = __builtin_bit_cast(unsigned, f);
  u += 0x7FFFu + ((u >> 16) & 1u);   // round-to-nearest-even
  return (unsigned short)(u >> 16);
}

__device__ __forceinline__ void gl_lds16(const void* g, void* l) {
  __builtin_amdgcn_global_load_lds(
      (const __attribute__((address_space(1))) void*)g,
      (__attribute__((address_space(3))) void*)l, 16, 0, 0);
}

// ---------- kernel 1: x (f32) -> bf16 ----------
__global__ __launch_bounds__(256) void cvt_x(const float* __restrict__ x,
                                             ushort_t* __restrict__ xb) {
  size_t i = ((size_t)blockIdx.x * 256 + threadIdx.x) * 8;
  float4 v0 = *(const float4*)(x + i);
  float4 v1 = *(const float4*)(x + i + 4);
  union { ushort_t s[8]; uint4 v; } o;
  o.s[0] = f2bf(v0.x); o.s[1] = f2bf(v0.y); o.s[2] = f2bf(v0.z); o.s[3] = f2bf(v0.w);
  o.s[4] = f2bf(v1.x); o.s[5] = f2bf(v1.y); o.s[6] = f2bf(v1.z); o.s[7] = f2bf(v1.w);
  *(uint4*)(xb + i) = o.v;
}

// ---------- kernel 2: W_eff = W + A@B, stored bf16 ----------
__global__ __launch_bounds__(256) void build_weff(const float* __restrict__ W,
                                                  const float* __restrict__ A,
                                                  const float* __restrict__ B,
                                                  ushort_t* __restrict__ Weff) {
  const int K = 4096, R = 16;
  const int n = blockIdx.y;
  const int k = (blockIdx.x * 256 + threadIdx.x) * 4;
  float4 w = *(const float4*)(W + (size_t)n * K + k);
  float a0 = w.x, a1 = w.y, a2 = w.z, a3 = w.w;
#pragma unroll
  for (int r = 0; r < R; ++r) {
    float a = A[n * R + r];
    float4 b = *(const float4*)(B + (size_t)r * K + k);
    a0 += a * b.x; a1 += a * b.y; a2 += a * b.z; a3 += a * b.w;
  }
  union { ushort_t s[4]; uint2 v; } o;
  o.s[0] = f2bf(a0); o.s[1] = f2bf(a1); o.s[2] = f2bf(a2); o.s[3] = f2bf(a3);
  *(uint2*)(Weff + (size_t)n * K + k) = o.v;
}

// ---------- kernel 3: 256x256 8-phase bf16 GEMM (faithful m201 port) ----------
// C[M][N] = Xb[M][K] * Wb[N][K]^T. BM=BN=256, BK=64. 8 waves (2M x 4N),
// per-wave C = 128x64 = acc[8][4] f32x4; 64 MFMA/wave/K-tile.
// LDS: [2 dbuf][Ah0,Ah1,Bh0,Bh1][128 rows][64 cols] bf16 = 128 KiB.
//   Row-halves: Ah = X rows bm+h*128..+127; Bh = W rows bn+h*128..+127.
//   Wave wm reads only A-half wm; wave wn reads B-half wn>>1, rows (wn&1)*64+...
// Swizzle (m201 st_16x32): phys = logical ^ ((logical>>9)&1)<<5. For frag reads,
// logical bit9 = row bit2 = (l>>2)&1 -> lane-constant XOR folded into ONE base
// VGPR; all 24 ds_reads are base + compile-time immediate (mi*2048 + kh*64).
// Phases per K-tile (quadrant x K=64, operands held in regs across phases):
//   Ph1: rd a[0-3][kh0,1] (8) + b[0-1][kh0,1] (4); stage Ah1(t+1)->buf^1;
//        lgkmcnt(8); BAR; lgkm0; 16 MFMA (m0-3 x n0-1); BAR
//   Ph2: rd a[4-7][kh0,1] (8);                       16 MFMA (m4-7 x n0-1)
//   Ph3: rd b[2-3][kh0,1] (4); stage Ah0(t+2)->buf;  16 MFMA (m0-3 x n2-3)
//   Ph4: no reads; stage Bh0,Bh1(t+2)->buf; vmcnt(6);16 MFMA (m4-7 x n2-3)
// WAR-safe: A-halves last read Ph2 (stage at Ph3+), B-halves last read Ph3
// (stage at Ph4); Ah1 of buf^1 last read Ph2(t-1) (stage at Ph1(t)).
// vmcnt(6) at Ph4 retires Ph1's pair -> tile t+1 fully landed before its BAR.

__device__ __forceinline__ void stage_half(const ushort_t* __restrict__ G, int grow0, int kc,
                                           ushort_t* half, int tid) {
#pragma unroll
  for (int r = 0; r < 2; ++r) {
    const int P = (r * 512 + tid) * 16;            // linear LDS byte (rule 21)
    const int L = P ^ (((P >> 9) & 1) << 5);        // logical byte (involution)
    const int row = L >> 7;                         // 0..127
    const int colb = L & 127;                       // byte within row
    const ushort_t* src = G + (size_t)(grow0 + row) * 4096 + kc + (colb >> 1);
    char* dst = (char*)half + (size_t)((r * 512 + (tid & ~63)) * 16); // wave-uniform
    gl_lds16(src, dst);
  }
}

__global__ __launch_bounds__(512) void gemm256(const ushort_t* __restrict__ Xb,
                                               const ushort_t* __restrict__ Wb,
                                               float* __restrict__ C) {
  const int N = 4096;
  const int NT = 4096 / 64;                 // 64 K-tiles
  __shared__ __align__(16) ushort_t lds[2][4][128 * 64];  // [buf][Ah0,Ah1,Bh0,Bh1]

  const int tid = threadIdx.x;
  const int l   = tid & 63;
  const int w   = tid >> 6;
  const int wm  = w >> 2;                   // 0..1
  const int wn  = w & 3;                    // 0..3

  // T1: bijective XCD chunking — 512 blocks = 8 chunks of 8x8 tiles (grid 32x16)
  const int bid = blockIdx.x;
  const int c = bid & 7, q = bid >> 3;
  const int tm = (c >> 1) * 8 + (q >> 3);   // 0..31
  const int tn = (c & 1) * 8 + (q & 7);     // 0..15
  const int bm = tm * 256, bn = tn * 256;

  // fragment read base (byte, swizzled): logical = (l&15)*128 + (l>>4)*16,
  // bit9 of any frag logical = (l>>2)&1 -> fold XOR into base.
  const int rb = (((l & 15) * 128) + ((l >> 4) * 16)) ^ (((l >> 2) & 1) << 5);

  f32x4 acc[8][4];
#pragma unroll
  for (int i = 0; i < 8; ++i)
#pragma unroll
    for (int j = 0; j < 4; ++j) acc[i][j] = (f32x4)(0.0f);

  // prologue: tile0 all 4 halves + tile1 {Ah0,Bh0,Bh1}; vmcnt(6) -> tile0 landed
  stage_half(Wb, bn,       0,  lds[0][2], tid);
  stage_half(Xb, bm,       0,  lds[0][0], tid);
  stage_half(Wb, bn + 128, 0,  lds[0][3], tid);
  stage_half(Xb, bm + 128, 0,  lds[0][1], tid);
  stage_half(Wb, bn,       64, lds[1][2], tid);
  stage_half(Xb, bm,       64, lds[1][0], tid);
  stage_half(Wb, bn + 128, 64, lds[1][3], tid);
  VM6();
  BAR();

  short8 a[8][2];     // a[mi][kh], held Ph1..Ph4
  short8 bb[2][2];    // b[ni&1][kh]: n0-1 during Ph1-2, n2-3 during Ph3-4

#define RD(P_) (*(const short8*)(P_))

  int cur = 0;
  for (int t = 0; t < NT; ++t) {
    const char* Ab = (const char*)lds[cur][wm] + rb;
    const char* Bb = (const char*)lds[cur][2 + (wn >> 1)] + (wn & 1) * 8192 + rb;
    const int kc1 = (t + 1) * 64, kc2 = (t + 2) * 64;

    // ---- Ph1: rd a0-3 + b0-1; stage Ah1(t+1); 16 MFMA m0-3 x n0-1 ----
#pragma unroll
    for (int mi = 0; mi < 4; ++mi) {
      a[mi][0] = RD(Ab + mi * 2048);
      a[mi][1] = RD(Ab + mi * 2048 + 64);
    }
#pragma unroll
    for (int ni = 0; ni < 2; ++ni) {
      bb[ni][0] = RD(Bb + ni * 2048);
      bb[ni][1] = RD(Bb + ni * 2048 + 64);
    }
    if (t + 1 < NT) stage_half(Xb, bm + 128, kc1, lds[cur ^ 1][1], tid);
    LGKM8();
    BAR(); LGKM0(); PRIO(1);
#pragma unroll
    for (int kh = 0; kh < 2; ++kh)
#pragma unroll
      for (int mi = 0; mi < 4; ++mi)
#pragma unroll
        for (int ni = 0; ni < 2; ++ni)
          acc[mi][ni] = MFMA(a[mi][kh], bb[ni][kh], acc[mi][ni]);
    PRIO(0); BAR();

    // ---- Ph2: rd a4-7; 16 MFMA m4-7 x n0-1 ----
#pragma unroll
    for (int mi = 4; mi < 8; ++mi) {
      a[mi][0] = RD(Ab + mi * 2048);
      a[mi][1] = RD(Ab + mi * 2048 + 64);
    }
    BAR(); LGKM0(); PRIO(1);
#pragma unroll
    for (int kh = 0; kh < 2; ++kh)
#pragma unroll
      for (int mi = 4; mi < 8; ++mi)
#pragma unroll
        for (int ni = 0; ni < 2; ++ni)
          acc[mi][ni] = MFMA(a[mi][kh], bb[ni][kh], acc[mi][ni]);
    PRIO(0); BAR();

    // ---- Ph3: rd b2-3; stage Ah0(t+2); 16 MFMA m0-3 x n2-3 ----
#pragma unroll
    for (int ni = 0; ni < 2; ++ni) {
      bb[ni][0] = RD(Bb + (2 + ni) * 2048);
      bb[ni][1] = RD(Bb + (2 + ni) * 2048 + 64);
    }
    if (t + 2 < NT) stage_half(Xb, bm, kc2, lds[cur][0], tid);
    BAR(); LGKM0(); PRIO(1);
#pragma unroll
    for (int kh = 0; kh < 2; ++kh)
#pragma unroll
      for (int mi = 0; mi < 4; ++mi)
#pragma unroll
        for (int ni = 0; ni < 2; ++ni)
          acc[mi][ni + 2] = MFMA(a[mi][kh], bb[ni][kh], acc[mi][ni + 2]);
    PRIO(0); BAR();

    // ---- Ph4: stage Bh0,Bh1(t+2); vmcnt; 16 MFMA m4-7 x n2-3 ----
    if (t + 2 < NT) {
      stage_half(Wb, bn,       kc2, lds[cur][2], tid);
      stage_half(Wb, bn + 128, kc2, lds[cur][3], tid);
      VM6();
    } else {
      VM0();
    }
    BAR(); PRIO(1);
#pragma unroll
    for (int kh = 0; kh < 2; ++kh)
#pragma unroll
      for (int mi = 4; mi < 8; ++mi)
#pragma unroll
        for (int ni = 0; ni < 2; ++ni)
          acc[mi][ni + 2] = MFMA(a[mi][kh], bb[ni][kh], acc[mi][ni + 2]);
    PRIO(0); BAR();

    cur ^= 1;
  }

  // epilogue: C/D layout col = lane&15, row = (lane>>4)*4 + j
  const int erow = bm + wm * 128 + (l >> 4) * 4;
  const int ecol = bn + wn * 64 + (l & 15);
#pragma unroll
  for (int mi = 0; mi < 8; ++mi) {
#pragma unroll
    for (int ni = 0; ni < 4; ++ni) {
      float* cp = C + (size_t)(erow + mi * 16) * N + ecol + ni * 16;
#pragma unroll
      for (int j = 0; j < 4; ++j) cp[(size_t)j * N] = acc[mi][ni][j];
    }
  }
}

extern "C" void kernel_launch(void* const* d_in, const int* in_sizes, int n_in,
                              void* d_out, int out_size, void* d_ws, size_t ws_size,
                              hipStream_t stream) {
  const float* x = (const float*)d_in[0];   // [8192, 4096]
  const float* W = (const float*)d_in[1];   // [4096, 4096]
  const float* A = (const float*)d_in[2];   // [4096, 16]
  const float* B = (const float*)d_in[3];   // [16, 4096]
  float* out = (float*)d_out;               // [8192, 4096]

  ushort_t* xb = (ushort_t*)d_ws;                                    // 64 MB
  ushort_t* wb = (ushort_t*)((char*)d_ws + (size_t)8192 * 4096 * 2); // 32 MB

  cvt_x<<<16384, 256, 0, stream>>>(x, xb);
  dim3 gw(4, 4096);
  build_weff<<<gw, 256, 0, stream>>>(W, A, B, wb);
  gemm256<<<512, 512, 0, stream>>>(xb, wb, out);  // grid 32x16 tiles, XCD-chunked
}